// Round 10
// baseline (581.962 us; speedup 1.0000x reference)
//
#include <hip/hip_runtime.h>
#include <hip/hip_bf16.h>

typedef __hip_bfloat16 bf16;
typedef short s8v __attribute__((ext_vector_type(8)));
typedef float f4v __attribute__((ext_vector_type(4)));

#define NN 20000
#define NE 160000
#define BN_EPS 1e-5f
#define NB 79   // cdiv(NN,256)

#define GF_BIAS 1
#define GF_RELU 2

static __device__ __forceinline__ float b2f(const bf16 x){ return __bfloat162float(x); }
static __device__ __forceinline__ float bits2f(unsigned int u){ return __uint_as_float(u << 16); }
static __device__ __forceinline__ unsigned short f2bits(float f){
  bf16 h = __float2bfloat16(f);
  unsigned short u; __builtin_memcpy(&u, &h, 2); return u;
}
static __device__ __forceinline__ float lrelu(float v){ return (v > 0.f) ? v : 0.2f * v; }

static inline int cdiv(int a, int b){ return (a + b - 1) / b; }

// async global->LDS, 16B per lane (wave-uniform LDS base + lane*16; lanes of a
// wave pass contiguous lds ptrs so the linear layout matches).
static __device__ __forceinline__ void gload16(const short* g, short* l){
  __builtin_amdgcn_global_load_lds(
      (const __attribute__((address_space(1))) unsigned int*)g,
      (__attribute__((address_space(3))) unsigned int*)l, 16, 0, 0);
}

// ---------------- diagnostics ----------------

__global__ void k_chk_bf(const unsigned short* __restrict__ x, int n, int code,
                         int* __restrict__ diag){
  bool bad = false;
  for (int k = blockIdx.x * 256 + threadIdx.x; k < n; k += gridDim.x * 256)
    if ((x[k] & 0x7F80u) == 0x7F80u) bad = true;
  if (bad) atomicCAS(diag, 0, code);
}

__global__ void k_diag_out(const int* __restrict__ diag, float* __restrict__ out){
  int d = *diag;
  if (d == 0) return;
  int i = blockIdx.x * 256 + threadIdx.x;
  if (i < NN) out[i] = (float)(d * 100);
}

// ---------------- CSR build (hierarchical, coalesced) ----------------

__global__ void k_ideg(const int* __restrict__ dst, int* __restrict__ ideg){
  int e = blockIdx.x * 256 + threadIdx.x;
  if (e < NE) atomicAdd(&ideg[dst[e]], 1);
}

__global__ __launch_bounds__(256) void k_scan1(const int* __restrict__ ideg,
                                               int* __restrict__ tmp,
                                               int* __restrict__ bsum){
  __shared__ int lds[256];
  int tid = threadIdx.x;
  int i = blockIdx.x * 256 + tid;
  int v = (i < NN) ? ideg[i] : 0;
  lds[tid] = v;
  __syncthreads();
  for (int off = 1; off < 256; off <<= 1){
    int t = (tid >= off) ? lds[tid - off] : 0;
    __syncthreads();
    lds[tid] += t;
    __syncthreads();
  }
  if (i < NN) tmp[i] = lds[tid];
  if (tid == 255) bsum[blockIdx.x] = lds[255];
}

__global__ __launch_bounds__(128) void k_scan2(const int* __restrict__ bsum,
                                               int* __restrict__ boff){
  __shared__ int lds[128];
  int tid = threadIdx.x;
  int v = (tid < NB) ? bsum[tid] : 0;
  lds[tid] = v;
  __syncthreads();
  for (int off = 1; off < 128; off <<= 1){
    int t = (tid >= off) ? lds[tid - off] : 0;
    __syncthreads();
    lds[tid] += t;
    __syncthreads();
  }
  if (tid < NB) boff[tid] = lds[tid] - v;
}

__global__ __launch_bounds__(256) void k_scan3(const int* __restrict__ ideg,
                                               const int* __restrict__ boff,
                                               int* __restrict__ rowptr,
                                               int* __restrict__ cursor,
                                               float* __restrict__ dg,
                                               float* __restrict__ dc,
                                               float* __restrict__ ic){
  int i = blockIdx.x * 256 + threadIdx.x;
  if (i == 0) rowptr[NN] = NE;
  if (i >= NN) return;
  int v = ideg[i];
  int excl = cursor[i] - v + boff[blockIdx.x];
  rowptr[i] = excl;
  cursor[i] = excl;
  float d = (float)v;
  dg[i] = rsqrtf(d + 1.0f);
  dc[i] = (d > 0.f) ? rsqrtf(d) : 0.f;
  ic[i] = 1.0f / fmaxf(d, 1.0f);
}

__global__ void k_fill(const int* __restrict__ src, const int* __restrict__ dst,
                       int* __restrict__ cursor, int* __restrict__ colsrc){
  int e = blockIdx.x * 256 + threadIdx.x;
  if (e >= NE) return;
  int pos = atomicAdd(&cursor[dst[e]], 1);
  colsrc[pos] = src[e];
}

// ---- batched weight prep ----

struct WtPack {
  const float* W[10]; short* hi[10]; short* lo[10];
  int K[10]; int nshift[10]; int base[11];
};

__global__ __launch_bounds__(256) void k_wtall(WtPack p){
  int idx = blockIdx.x * 256 + threadIdx.x;
  if (idx >= p.base[10]) return;
  int seg = 0;
#pragma unroll
  for (int i = 1; i < 10; i++) seg += (idx >= p.base[i]) ? 1 : 0;
  int local = idx - p.base[seg];
  int K = p.K[seg], ns = p.nshift[seg];
  int n = local & ((1 << ns) - 1), k = local >> ns;
  float w = p.W[seg][local];
  unsigned short h = f2bits(w);
  unsigned short l = f2bits(w - bits2f(h));
  p.hi[seg][(size_t)n * K + k] = (short)h;
  p.lo[seg][(size_t)n * K + k] = (short)l;
}

// ---------------- gather ----------------

__global__ void k_gather(const int* __restrict__ uidx, const int* __restrict__ iidx,
                         const float* __restrict__ ue, const float* __restrict__ ie,
                         bf16* __restrict__ x0){
  int idx = blockIdx.x * 256 + threadIdx.x;
  if (idx >= NN * 128) return;
  int i = idx >> 7, c = idx & 127;
  float v = (c < 64) ? ue[(size_t)uidx[i] * 64 + c] : ie[(size_t)iidx[i] * 64 + (c - 64)];
  x0[idx] = __float2bfloat16(v);
}

// ------- MFMA GEMM, 64x64 tile, hi/lo fused, reg-staging (SAGE/Cheb npass=2) -------

__global__ __launch_bounds__(256) void k_mm64(
    const bf16* A0, const short* B0h, const short* B0l, int K0,
    const bf16* A1, const short* B1h, const short* B1l, int K1,
    const float* __restrict__ bias, bf16* __restrict__ C,
    int M, int Ncol, int flags, int npass){
  __shared__ short As[64][72];    // 64 K-shorts + 8 pad (16B-aligned rows)
  __shared__ short Bhs[64][72];
  __shared__ short Bls[64][72];
  const int tid = threadIdx.x;
  const int bid = blockIdx.y * gridDim.x + blockIdx.x;
  const int total = gridDim.x * gridDim.y;
  const int L = (bid & 7) * (total >> 3) + (bid >> 3);
  const int row0 = (L / gridDim.x) * 64, col0 = (L % gridDim.x) * 64;
  if (row0 >= M) return;
  const int wid = tid >> 6, lane = tid & 63;
  const int wr = (wid >> 1) * 32, wc = (wid & 1) * 32;
  const int lr = lane & 15, lq = lane >> 4;
  const int sr = tid >> 2, sq = (tid & 3) * 16;  // staging: row sr, 16 shorts from sq

  f4v acc[2][2];
#pragma unroll
  for (int i = 0; i < 2; i++)
#pragma unroll
    for (int j = 0; j < 2; j++)
      acc[i][j] = f4v{0.f, 0.f, 0.f, 0.f};

  const bf16* Aarr[2] = {A0, A1};
  const short* Bharr[2] = {B0h, B1h};
  const short* Blarr[2] = {B0l, B1l};
  const int Karr[2] = {K0, K1};

  const bool arow_ok = (row0 + sr) < M;

  for (int p = 0; p < npass; p++){
    const short* A = (const short*)Aarr[p];
    const short* Bh = Bharr[p];
    const short* Bl = Blarr[p];
    const int K = Karr[p];
    const short* arow = A + (size_t)(row0 + sr) * K + sq;
    const short* bhrow = Bh + (size_t)(col0 + sr) * K + sq;
    const short* blrow = Bl + (size_t)(col0 + sr) * K + sq;

    // prologue: load tile k0=0 into registers
    uint4 ra0 = make_uint4(0,0,0,0), ra1 = make_uint4(0,0,0,0);
    if (arow_ok){ ra0 = *(const uint4*)(arow); ra1 = *(const uint4*)(arow + 8); }
    uint4 rb0 = *(const uint4*)(bhrow), rb1 = *(const uint4*)(bhrow + 8);
    uint4 rc0 = *(const uint4*)(blrow), rc1 = *(const uint4*)(blrow + 8);

    for (int k0 = 0; k0 < K; k0 += 64){
      // commit staged registers to LDS
      *(uint4*)&As[sr][sq] = ra0;  *(uint4*)&As[sr][sq + 8] = ra1;
      *(uint4*)&Bhs[sr][sq] = rb0; *(uint4*)&Bhs[sr][sq + 8] = rb1;
      *(uint4*)&Bls[sr][sq] = rc0; *(uint4*)&Bls[sr][sq + 8] = rc1;
      __syncthreads();
      // prefetch next tile while this one computes (overlaps global latency)
      if (k0 + 64 < K){
        int off = k0 + 64;
        if (arow_ok){ ra0 = *(const uint4*)(arow + off); ra1 = *(const uint4*)(arow + off + 8); }
        rb0 = *(const uint4*)(bhrow + off); rb1 = *(const uint4*)(bhrow + off + 8);
        rc0 = *(const uint4*)(blrow + off); rc1 = *(const uint4*)(blrow + off + 8);
      }
#pragma unroll
      for (int t = 0; t < 2; t++){
        s8v a[2], bh2[2], bl2[2];
#pragma unroll
        for (int i = 0; i < 2; i++) a[i] = *(const s8v*)&As[wr + i * 16 + lr][t * 32 + lq * 8];
#pragma unroll
        for (int j = 0; j < 2; j++){
          bh2[j] = *(const s8v*)&Bhs[wc + j * 16 + lr][t * 32 + lq * 8];
          bl2[j] = *(const s8v*)&Bls[wc + j * 16 + lr][t * 32 + lq * 8];
        }
#pragma unroll
        for (int i = 0; i < 2; i++)
#pragma unroll
          for (int j = 0; j < 2; j++){
            acc[i][j] = __builtin_amdgcn_mfma_f32_16x16x32_bf16(a[i], bh2[j], acc[i][j], 0, 0, 0);
            acc[i][j] = __builtin_amdgcn_mfma_f32_16x16x32_bf16(a[i], bl2[j], acc[i][j], 0, 0, 0);
          }
      }
      __syncthreads();
    }
  }

#pragma unroll
  for (int i = 0; i < 2; i++){
#pragma unroll
    for (int rg = 0; rg < 4; rg++){
      int row = row0 + wr + i * 16 + lq * 4 + rg;
      if (row >= M) continue;
#pragma unroll
      for (int j = 0; j < 2; j++){
        int col = col0 + wc + j * 16 + lr;
        float v = acc[i][j][rg];
        if (flags & GF_BIAS) v += bias[col];
        if (flags & GF_RELU) v = fmaxf(v, 0.f);
        C[(size_t)row * Ncol + col] = __float2bfloat16(v);
      }
    }
  }
}

// ------- MFMA GEMM, 128x64 tile, gload_lds staging + involution swizzle -------
// R7 best for large grids (MLP2): 32KB LDS, 5 blk/CU, 2 barriers/K-step,
// conflicts 0 (PMC-verified). UNCHANGED.

__global__ __launch_bounds__(256) void k_mmw(
    const bf16* A0, const short* B0h, const short* B0l, int K,
    const float* __restrict__ bias, bf16* __restrict__ C,
    int M, int Ncol, int flags){
  __shared__ short As[128 * 64];
  __shared__ short Bhs[64 * 64];
  __shared__ short Bls[64 * 64];
  const int tid = threadIdx.x;
  const int bid = blockIdx.y * gridDim.x + blockIdx.x;
  const int total = gridDim.x * gridDim.y;
  const int L = (bid & 7) * (total >> 3) + (bid >> 3);
  const int row0 = (L / gridDim.x) * 128, col0 = (L % gridDim.x) * 64;
  if (row0 >= M) return;
  const int wid = tid >> 6, lane = tid & 63;
  const int wr2 = (wid >> 1) * 64, wc2 = (wid & 1) * 32;
  const int lr = lane & 15, lq = lane >> 4;
  const int rx = lr & 7;    // read-side XOR key (row & 7 == lr & 7 here)

  f4v acc[4][2];
#pragma unroll
  for (int i = 0; i < 4; i++)
#pragma unroll
    for (int j = 0; j < 2; j++)
      acc[i][j] = f4v{0.f, 0.f, 0.f, 0.f};

  // staging: A = 1024 chunks (128 rows x 8), B = 512 chunks each.
  // LDS chunk (r,c) holds GLOBAL chunk c ^ (r&7) of row r (involution).
  const short* A = (const short*)A0;
  const short* asrc[4]; int adst[4];
#pragma unroll
  for (int i = 0; i < 4; i++){
    int ci = i * 256 + tid;
    int r = ci >> 3, sg = ci & 7;
    int ar = row0 + r; if (ar > M - 1) ar = M - 1;   // clamp ragged M
    asrc[i] = A + (size_t)ar * K + ((sg ^ (r & 7)) * 8);
    adst[i] = ci * 8;
  }
  const short* bhsrc[2]; const short* blsrc[2]; int bdst[2];
#pragma unroll
  for (int i = 0; i < 2; i++){
    int ci = i * 256 + tid;
    int r = ci >> 3, sg = ci & 7;
    int sc = (sg ^ (r & 7)) * 8;
    bhsrc[i] = B0h + (size_t)(col0 + r) * K + sc;
    blsrc[i] = B0l + (size_t)(col0 + r) * K + sc;
    bdst[i] = ci * 8;
  }

  for (int k0 = 0; k0 < K; k0 += 64){
    __syncthreads();      // all waves done reading LDS before overwrite
#pragma unroll
    for (int i = 0; i < 4; i++) gload16(asrc[i] + k0, As + adst[i]);
#pragma unroll
    for (int i = 0; i < 2; i++){
      gload16(bhsrc[i] + k0, Bhs + bdst[i]);
      gload16(blsrc[i] + k0, Bls + bdst[i]);
    }
    __syncthreads();      // compiler drains vmcnt(0) before s_barrier
#pragma unroll
    for (int t = 0; t < 2; t++){
      s8v a[4], bh2[2], bl2[2];
      const int ch0 = (((t << 2) | lq) ^ rx) * 8;   // swizzled chunk offset
#pragma unroll
      for (int i = 0; i < 4; i++)
        a[i] = *(const s8v*)&As[(wr2 + i * 16 + lr) * 64 + ch0];
#pragma unroll
      for (int j = 0; j < 2; j++){
        bh2[j] = *(const s8v*)&Bhs[(wc2 + j * 16 + lr) * 64 + ch0];
        bl2[j] = *(const s8v*)&Bls[(wc2 + j * 16 + lr) * 64 + ch0];
      }
#pragma unroll
      for (int i = 0; i < 4; i++)
#pragma unroll
        for (int j = 0; j < 2; j++){
          acc[i][j] = __builtin_amdgcn_mfma_f32_16x16x32_bf16(a[i], bh2[j], acc[i][j], 0, 0, 0);
          acc[i][j] = __builtin_amdgcn_mfma_f32_16x16x32_bf16(a[i], bl2[j], acc[i][j], 0, 0, 0);
        }
    }
  }

#pragma unroll
  for (int i = 0; i < 4; i++){
#pragma unroll
    for (int rg = 0; rg < 4; rg++){
      int row = row0 + wr2 + i * 16 + lq * 4 + rg;
      if (row >= M) continue;
#pragma unroll
      for (int j = 0; j < 2; j++){
        int col = col0 + wc2 + j * 16 + lr;
        float v = acc[i][j][rg];
        if (flags & GF_BIAS) v += bias[col];
        if (flags & GF_RELU) v = fmaxf(v, 0.f);
        C[(size_t)row * Ncol + col] = __float2bfloat16(v);
      }
    }
  }
}

// ------- MFMA GEMM, 64x64 tile, BK=32, gload_lds + swizzle, 12KB LDS -------
// For grid-starved shapes (GCN1/GCN2/GAT projections: N<=256 -> <=628 blocks
// at BM=128 = 2.45 blk/CU) and LDS-capped MLP1. BM=64 doubles ny; 12KB LDS
// lifts the residency cap to 8 blocks/CU (32 waves, the wave limit).
// Swizzle: R4-verified BK=32 involution (key (r>>1)&3), PMC 0 conflicts,
// refcheck'd. 4 waves of 32x32 sub-tiles (k_mm64 wave layout). Per K-32 step:
// 3 DMAs/thread, 16 MFMAs/wave (192 B/MFMA, same intensity as k_mmw).
// Requires K % 32 == 0, Ncol % 64 == 0. Ragged M: clamp staged row,
// guarded stores.

__global__ __launch_bounds__(256) void k_mms(
    const bf16* A0, const short* B0h, const short* B0l, int K,
    const float* __restrict__ bias, bf16* __restrict__ C,
    int M, int Ncol, int flags){
  __shared__ short As[64 * 32];
  __shared__ short Bhs[64 * 32];
  __shared__ short Bls[64 * 32];
  const int tid = threadIdx.x;
  const int bid = blockIdx.y * gridDim.x + blockIdx.x;
  const int total = gridDim.x * gridDim.y;
  const int L = (bid & 7) * (total >> 3) + (bid >> 3);
  const int row0 = (L / gridDim.x) * 64, col0 = (L % gridDim.x) * 64;
  if (row0 >= M) return;
  const int wid = tid >> 6, lane = tid & 63;
  const int wr = (wid >> 1) * 32, wc = (wid & 1) * 32;
  const int lr = lane & 15, lq = lane >> 4;
  const int rx = (lr >> 1) & 3;       // read-side key ((row>>1)&3 == (lr>>1)&3)
  const int ch = (lq ^ rx) * 8;       // swizzled chunk offset (shorts)

  f4v acc[2][2];
#pragma unroll
  for (int i = 0; i < 2; i++)
#pragma unroll
    for (int j = 0; j < 2; j++)
      acc[i][j] = f4v{0.f, 0.f, 0.f, 0.f};

  // staging: 256 16B chunks per array (64 rows x 4); 1 chunk/thread each.
  // LDS chunk (r,c) holds GLOBAL chunk c ^ ((r>>1)&3) of row r (involution).
  const short* A = (const short*)A0;
  const int r = tid >> 2, c = tid & 3;
  const int sc = (c ^ ((r >> 1) & 3)) * 8;
  int ar = row0 + r; if (ar > M - 1) ar = M - 1;   // clamp ragged M
  const short* asrc  = A   + (size_t)ar * K + sc;
  const short* bhsrc = B0h + (size_t)(col0 + r) * K + sc;
  const short* blsrc = B0l + (size_t)(col0 + r) * K + sc;
  const int dst = tid * 8;

  for (int k0 = 0; k0 < K; k0 += 32){
    __syncthreads();      // all waves done reading LDS before overwrite
    gload16(asrc + k0, As + dst);
    gload16(bhsrc + k0, Bhs + dst);
    gload16(blsrc + k0, Bls + dst);
    __syncthreads();      // compiler drains vmcnt(0) before s_barrier
    {
      s8v a[2], bh2[2], bl2[2];
#pragma unroll
      for (int i = 0; i < 2; i++)
        a[i] = *(const s8v*)&As[(wr + i * 16 + lr) * 32 + ch];
#pragma unroll
      for (int j = 0; j < 2; j++){
        bh2[j] = *(const s8v*)&Bhs[(wc + j * 16 + lr) * 32 + ch];
        bl2[j] = *(const s8v*)&Bls[(wc + j * 16 + lr) * 32 + ch];
      }
#pragma unroll
      for (int i = 0; i < 2; i++)
#pragma unroll
        for (int j = 0; j < 2; j++){
          acc[i][j] = __builtin_amdgcn_mfma_f32_16x16x32_bf16(a[i], bh2[j], acc[i][j], 0, 0, 0);
          acc[i][j] = __builtin_amdgcn_mfma_f32_16x16x32_bf16(a[i], bl2[j], acc[i][j], 0, 0, 0);
        }
    }
  }

#pragma unroll
  for (int i = 0; i < 2; i++){
#pragma unroll
    for (int rg = 0; rg < 4; rg++){
      int row = row0 + wr + i * 16 + lq * 4 + rg;
      if (row >= M) continue;
#pragma unroll
      for (int j = 0; j < 2; j++){
        int col = col0 + wc + j * 16 + lr;
        float v = acc[i][j][rg];
        if (flags & GF_BIAS) v += bias[col];
        if (flags & GF_RELU) v = fmaxf(v, 0.f);
        C[(size_t)row * Ncol + col] = __float2bfloat16(v);
      }
    }
  }
}

// ------- CSR aggregation: 4 cols/thread, 4-edge batched -------

__global__ __launch_bounds__(256) void k_agg(
    const int* __restrict__ rowptr, const int* __restrict__ colsrc,
    const bf16* __restrict__ x, const float* __restrict__ wn,
    const float* __restrict__ icv, const float* __restrict__ bias,
    float* __restrict__ outf, bf16* __restrict__ outb,
    int qshift, int mode){
  int idx = blockIdx.x * 256 + threadIdx.x;
  int total = NN << qshift;
  if (idx >= total) return;
  int d = idx >> qshift, q = idx & ((1 << qshift) - 1);
  int F = 4 << qshift;
  int c = q * 4;
  int r0 = rowptr[d], r1 = rowptr[d + 1];
  float s0 = 0.f, s1 = 0.f, s2 = 0.f, s3 = 0.f;
  const short* xs = (const short*)x;
  for (int r = r0; r < r1; r += 4){
    int n = r1 - r;
    int i0 = colsrc[r];
    int i1 = (n > 1) ? colsrc[r + 1] : 0;
    int i2 = (n > 2) ? colsrc[r + 2] : 0;
    int i3 = (n > 3) ? colsrc[r + 3] : 0;
    float w0 = (mode == 1) ? 1.f : wn[i0];
    float w1 = (n > 1) ? ((mode == 1) ? 1.f : wn[i1]) : 0.f;
    float w2 = (n > 2) ? ((mode == 1) ? 1.f : wn[i2]) : 0.f;
    float w3 = (n > 3) ? ((mode == 1) ? 1.f : wn[i3]) : 0.f;
    uint2 v0 = *(const uint2*)(xs + (size_t)i0 * F + c);
    uint2 v1 = *(const uint2*)(xs + (size_t)i1 * F + c);
    uint2 v2 = *(const uint2*)(xs + (size_t)i2 * F + c);
    uint2 v3 = *(const uint2*)(xs + (size_t)i3 * F + c);
    s0 += w0 * bits2f(v0.x & 0xffffu) + w1 * bits2f(v1.x & 0xffffu)
        + w2 * bits2f(v2.x & 0xffffu) + w3 * bits2f(v3.x & 0xffffu);
    s1 += w0 * bits2f(v0.x >> 16) + w1 * bits2f(v1.x >> 16)
        + w2 * bits2f(v2.x >> 16) + w3 * bits2f(v3.x >> 16);
    s2 += w0 * bits2f(v0.y & 0xffffu) + w1 * bits2f(v1.y & 0xffffu)
        + w2 * bits2f(v2.y & 0xffffu) + w3 * bits2f(v3.y & 0xffffu);
    s3 += w0 * bits2f(v0.y >> 16) + w1 * bits2f(v1.y >> 16)
        + w2 * bits2f(v2.y >> 16) + w3 * bits2f(v3.y >> 16);
  }
  if (mode == 0){
    float w = wn[d], w2 = w * w;
    uint2 vd = *(const uint2*)(xs + (size_t)d * F + c);
    float4 o;
    o.x = w * s0 + w2 * bits2f(vd.x & 0xffffu) + bias[c + 0];
    o.y = w * s1 + w2 * bits2f(vd.x >> 16)     + bias[c + 1];
    o.z = w * s2 + w2 * bits2f(vd.y & 0xffffu) + bias[c + 2];
    o.w = w * s3 + w2 * bits2f(vd.y >> 16)     + bias[c + 3];
    *(float4*)(outf + (size_t)d * F + c) = o;
  } else {
    float m = (mode == 1) ? icv[d] : -wn[d];
    unsigned int lo = (unsigned int)f2bits(s0 * m) | ((unsigned int)f2bits(s1 * m) << 16);
    unsigned int hi = (unsigned int)f2bits(s2 * m) | ((unsigned int)f2bits(s3 * m) << 16);
    *(uint2*)((short*)outb + (size_t)d * F + c) = make_uint2(lo, hi);
  }
}

// ---------------- batchnorm ----------------

__global__ void k_bn_stats(const float* __restrict__ x, float* __restrict__ stats, int F){
  int c = threadIdx.x & (F - 1);
  int rsub = threadIdx.x / F;
  int rpi = 256 / F;
  int r0 = blockIdx.x * 128;
  int rend = min(NN, r0 + 128);
  float s1 = 0.f, s2 = 0.f;
  for (int r = r0 + rsub; r < rend; r += rpi){
    float v = x[(size_t)r * F + c];
    s1 += v; s2 += v * v;
  }
  atomicAdd(&stats[c], s1);
  atomicAdd(&stats[F + c], s2);
}

__global__ void k_bn_apply(const float* __restrict__ x, const float* __restrict__ stats,
                           const float* __restrict__ g, const float* __restrict__ b,
                           int fshift, int total, bf16* __restrict__ out){
  int idx = blockIdx.x * 256 + threadIdx.x;
  if (idx >= total) return;
  int F = 1 << fshift;
  int c = idx & (F - 1);
  float mu = stats[c] * (1.0f / NN);
  float var = fmaxf(stats[F + c] * (1.0f / NN) - mu * mu, 0.f);
  float v = (x[idx] - mu) * rsqrtf(var + BN_EPS) * g[c] + b[c];
  out[idx] = __float2bfloat16(fmaxf(v, 0.f));
}

// ---------------- GAT ----------------

__global__ __launch_bounds__(256) void k_gat_alar(const bf16* __restrict__ xp,
                                                  const float* __restrict__ as_,
                                                  const float* __restrict__ ad_,
                                                  float* __restrict__ al,
                                                  float* __restrict__ ar){
  int d = blockIdx.x * 4 + (threadIdx.x >> 6);
  int lane = threadIdx.x & 63;
  if (d >= NN) return;
  int c0 = lane * 2;
  unsigned int p0 = *(const unsigned int*)((const short*)xp + (size_t)d * 256 + c0);
  unsigned int p1 = *(const unsigned int*)((const short*)xp + (size_t)d * 256 + 128 + c0);
  float x00 = bits2f(p0 & 0xffffu), x01 = bits2f(p0 >> 16);
  float x10 = bits2f(p1 & 0xffffu), x11 = bits2f(p1 >> 16);
  float sa0 = x00 * as_[c0] + x01 * as_[c0 + 1];
  float sd0 = x00 * ad_[c0] + x01 * ad_[c0 + 1];
  float sa1 = x10 * as_[128 + c0] + x11 * as_[128 + c0 + 1];
  float sd1 = x10 * ad_[128 + c0] + x11 * ad_[128 + c0 + 1];
#pragma unroll
  for (int off = 32; off > 0; off >>= 1){
    sa0 += __shfl_xor(sa0, off); sd0 += __shfl_xor(sd0, off);
    sa1 += __shfl_xor(sa1, off); sd1 += __shfl_xor(sd1, off);
  }
  if (lane == 0){
    al[d * 2] = sa0;     ar[d * 2] = sd0;
    al[d * 2 + 1] = sa1; ar[d * 2 + 1] = sd1;
  }
}

// Online-softmax single-pass GAT, 4 nodes/block (1 wave each), ZERO LDS.
// Broadcasts via __shfl; lanes >= nt carry w=0 so their edges contribute 0.

__global__ __launch_bounds__(256) void k_gat(const int* __restrict__ rowptr,
                                             const int* __restrict__ colsrc,
                                             const bf16* __restrict__ xp,
                                             const float* __restrict__ al,
                                             const float* __restrict__ ar,
                                             const float* __restrict__ bias,
                                             bf16* __restrict__ outb,
                                             const float* __restrict__ wp,
                                             const float* __restrict__ bp,
                                             float* __restrict__ outf){
  int lane = threadIdx.x & 63;
  int d = blockIdx.x * 4 + (threadIdx.x >> 6);
  if (d >= NN) return;
  int r0 = rowptr[d], r1 = rowptr[d + 1];
  float ard0 = ar[d * 2], ard1 = ar[d * 2 + 1];
  float e0 = lrelu(al[d * 2] + ard0);
  float e1 = lrelu(al[d * 2 + 1] + ard1);
  float m0 = e0, m1 = e1;                 // running max (uniform across lanes)
  float ps0 = (lane == 0) ? 1.f : 0.f;    // self term: exp(e0 - m0) = 1
  float ps1 = ps0;
  int c0 = lane * 2;
  float a00, a01, a10, a11;               // PV accum at weight exp(e_self-m)=1
  {
    unsigned int p0 = *(const unsigned int*)((const short*)xp + (size_t)d * 256 + c0);
    unsigned int p1 = *(const unsigned int*)((const short*)xp + (size_t)d * 256 + 128 + c0);
    a00 = bits2f(p0 & 0xffffu); a01 = bits2f(p0 >> 16);
    a10 = bits2f(p1 & 0xffffu); a11 = bits2f(p1 >> 16);
  }
  for (int t0 = r0; t0 < r1; t0 += 64){
    int nt = min(64, r1 - t0);
    float el0 = -3.4e38f, el1 = -3.4e38f;
    int s = 0;
    if (lane < nt){
      s = colsrc[t0 + lane];
      el0 = lrelu(al[s * 2] + ard0);
      el1 = lrelu(al[s * 2 + 1] + ard1);
    }
    // chunk max via shfl (in-register)
    float cm0 = el0, cm1 = el1;
#pragma unroll
    for (int off = 32; off > 0; off >>= 1){
      cm0 = fmaxf(cm0, __shfl_xor(cm0, off));
      cm1 = fmaxf(cm1, __shfl_xor(cm1, off));
    }
    float n0 = fmaxf(m0, cm0), n1 = fmaxf(m1, cm1);
    float sc0 = expf(m0 - n0), sc1 = expf(m1 - n1);
    ps0 *= sc0; ps1 *= sc1;
    a00 *= sc0; a01 *= sc0; a10 *= sc1; a11 *= sc1;
    m0 = n0; m1 = n1;
    // each lane computes ITS edge's weight once; denominator contribution
    float w0 = 0.f, w1 = 0.f;
    if (lane < nt){
      w0 = expf(el0 - m0);
      w1 = expf(el1 - m1);
      ps0 += w0; ps1 += w1;
    }
    // PV: 4-edge batched, broadcast via shfl (no LDS, no barriers)
    for (int r = 0; r < nt; r += 4){
      int sA = __shfl(s, r);     float wA0 = __shfl(w0, r),     wA1 = __shfl(w1, r);
      int sB = __shfl(s, r + 1); float wB0 = __shfl(w0, r + 1), wB1 = __shfl(w1, r + 1);
      int sC = __shfl(s, r + 2); float wC0 = __shfl(w0, r + 2), wC1 = __shfl(w1, r + 2);
      int sD = __shfl(s, r + 3); float wD0 = __shfl(w0, r + 3), wD1 = __shfl(w1, r + 3);
      unsigned int pA0 = *(const unsigned int*)((const short*)xp + (size_t)sA * 256 + c0);
      unsigned int pA1 = *(const unsigned int*)((const short*)xp + (size_t)sA * 256 + 128 + c0);
      unsigned int pB0 = *(const unsigned int*)((const short*)xp + (size_t)sB * 256 + c0);
      unsigned int pB1 = *(const unsigned int*)((const short*)xp + (size_t)sB * 256 + 128 + c0);
      unsigned int pC0 = *(const unsigned int*)((const short*)xp + (size_t)sC * 256 + c0);
      unsigned int pC1 = *(const unsigned int*)((const short*)xp + (size_t)sC * 256 + 128 + c0);
      unsigned int pD0 = *(const unsigned int*)((const short*)xp + (size_t)sD * 256 + c0);
      unsigned int pD1 = *(const unsigned int*)((const short*)xp + (size_t)sD * 256 + 128 + c0);
      a00 += wA0 * bits2f(pA0 & 0xffffu) + wB0 * bits2f(pB0 & 0xffffu)
           + wC0 * bits2f(pC0 & 0xffffu) + wD0 * bits2f(pD0 & 0xffffu);
      a01 += wA0 * bits2f(pA0 >> 16) + wB0 * bits2f(pB0 >> 16)
           + wC0 * bits2f(pC0 >> 16) + wD0 * bits2f(pD0 >> 16);
      a10 += wA1 * bits2f(pA1 & 0xffffu) + wB1 * bits2f(pB1 & 0xffffu)
           + wC1 * bits2f(pC1 & 0xffffu) + wD1 * bits2f(pD1 & 0xffffu);
      a11 += wA1 * bits2f(pA1 >> 16) + wB1 * bits2f(pB1 >> 16)
           + wC1 * bits2f(pC1 >> 16) + wD1 * bits2f(pD1 >> 16);
    }
  }
#pragma unroll
  for (int off = 32; off > 0; off >>= 1){
    ps0 += __shfl_xor(ps0, off);
    ps1 += __shfl_xor(ps1, off);
  }
  float v0 = 0.5f * (a00 / ps0 + a10 / ps1) + bias[c0];
  float v1 = 0.5f * (a01 / ps0 + a11 / ps1) + bias[c0 + 1];
  v0 = (v0 > 0.f) ? v0 : expm1f(v0);
  v1 = (v1 > 0.f) ? v1 : expm1f(v1);
  if (wp == nullptr){
    unsigned int packed = (unsigned int)f2bits(v0) | ((unsigned int)f2bits(v1) << 16);
    *(unsigned int*)((short*)outb + (size_t)d * 128 + c0) = packed;
  } else {
    float pv = v0 * wp[c0] + v1 * wp[c0 + 1];
#pragma unroll
    for (int off = 32; off > 0; off >>= 1) pv += __shfl_down(pv, off);
    if (lane == 0) outf[d] = pv + bp[0];
  }
}

// ---------------- host ----------------

extern "C" void kernel_launch(void* const* d_in, const int* in_sizes, int n_in,
                              void* d_out, int out_size, void* d_ws, size_t ws_size,
                              hipStream_t stream){
  const int* uidx = (const int*)d_in[0];
  const int* iidx = (const int*)d_in[1];
  const int* eidx = (const int*)d_in[2];
  const int* src = eidx;
  const int* dst = eidx + NE;
  const float* ue  = (const float*)d_in[3];
  const float* ie  = (const float*)d_in[4];
  const float* W1  = (const float*)d_in[5];  const float* b1  = (const float*)d_in[6];
  const float* W2  = (const float*)d_in[7];  const float* b2  = (const float*)d_in[8];
  const float* Wg1 = (const float*)d_in[9];  const float* bg1 = (const float*)d_in[10];
  const float* gamma1 = (const float*)d_in[11]; const float* beta1 = (const float*)d_in[12];
  const float* Wg2 = (const float*)d_in[13]; const float* bg2 = (const float*)d_in[14];
  const float* gamma2 = (const float*)d_in[15]; const float* beta2 = (const float*)d_in[16];
  const float* Wsl = (const float*)d_in[17]; const float* bsl = (const float*)d_in[18];
  const float* Wsr = (const float*)d_in[19];
  const float* Wc0 = (const float*)d_in[20]; const float* Wc1 = (const float*)d_in[21];
  const float* bc  = (const float*)d_in[22];
  const float* Wgat1 = (const float*)d_in[23]; const float* as1 = (const float*)d_in[24];
  const float* ad1 = (const float*)d_in[25];   const float* bgat1 = (const float*)d_in[26];
  const float* Wgat2 = (const float*)d_in[27]; const float* as2 = (const float*)d_in[28];
  const float* ad2 = (const float*)d_in[29];   const float* bgat2 = (const float*)d_in[30];
  const float* Wp  = (const float*)d_in[31];   const float* bp  = (const float*)d_in[32];

  // ---- workspace ----
  int* diag   = (int*)d_ws;
  int* ideg   = diag + 4;
  float* stats1 = (float*)(ideg + NN);
  float* stats2 = stats1 + 512;
  int* bsum   = (int*)(stats2 + 256);
  int* boff   = bsum + 128;
  int* rowptr = boff + 128;
  int* cursor = rowptr + NN + 4;
  int* colsrc = cursor + NN;
  float* dg = (float*)(colsrc + NE);
  float* dc = dg + NN;
  float* ic = dc + NN;
  float* al = ic + NN;
  float* ar = al + 2 * NN;
  short* w1h = (short*)(ar + 2 * NN);
  short* w1l = w1h + 131072;
  short* w2h = w1l + 131072;
  short* w2l = w2h + 524288;
  short* wg1h = w2l + 524288;
  short* wg1l = wg1h + 131072;
  short* wg2h = wg1l + 131072;
  short* wg2l = wg2h + 32768;
  short* wslh = wg2l + 32768;
  short* wsll = wslh + 16384;
  short* wsrh = wsll + 16384;
  short* wsrl = wsrh + 16384;
  short* wc0h = wsrl + 16384;
  short* wc0l = wc0h + 16384;
  short* wc1h = wc0l + 16384;
  short* wc1l = wc1h + 16384;
  short* wgat1h = wc1l + 16384;
  short* wgat1l = wgat1h + 32768;
  short* wgat2h = wgat1l + 32768;
  short* wgat2l = wgat2h + 32768;
  short* X0 = wgat2l + 32768;
  short* H1 = X0 + (size_t)NN * 128;

  // MLP intermediate H1: prefer single-shot M=20000 (occupancy lever).
  size_t h1rows = 20000;
  short* H2 = H1 + h1rows * 1024;
  {
    size_t need = (size_t)((char*)(H2 + (size_t)NN * 512) - (char*)d_ws);
    if (need > ws_size){
      h1rows = 10000;
      H2 = H1 + h1rows * 1024;
    }
  }

  bf16* x0b  = (bf16*)X0;
  bf16* h1b  = (bf16*)H1;
  bf16* h2b  = (bf16*)H2;
  bf16* xw1b = (bf16*)H1;
  float* g1f = (float*)H2;
  bf16* g1b  = (bf16*)(H1 + (size_t)NN * 256);
  bf16* xw2b = (bf16*)X0;
  float* x3f = (float*)H1;
  bf16* x3b  = (bf16*)H2;
  bf16* aggb = (bf16*)X0;
  bf16* x4b  = (bf16*)(H2 + (size_t)NN * 128);
  bf16* tx1b = (bf16*)X0;
  bf16* x5b  = (bf16*)(H2 + (size_t)NN * 256);
  bf16* xpb  = (bf16*)H1;
  bf16* x6b  = (bf16*)X0;

  auto mm = [&](const bf16* A1, const short* B1h, const short* B1l, int K1,
                const bf16* A2, const short* B2h, const short* B2l, int K2,
                const float* bias, bf16* C, int M, int N, int flags){
    int nx = N / 64;
    int ny = cdiv(M, 64);
    while ((nx * ny) & 7) ny++;
    dim3 g(nx, ny);
    int np = A2 ? 2 : 1;
    k_mm64<<<g, 256, 0, stream>>>(A1, B1h, B1l, K1, A2, B2h, B2l, K2,
                                  bias, C, M, N, flags, np);
  };

  // 128x64-tile gload_lds path (MLP2: big grid, best per-byte tile)
  auto mmw = [&](const bf16* A, const short* Bh, const short* Bl, int K,
                 const float* bias, bf16* C, int M, int N, int flags){
    int nx = N / 64;
    int ny = cdiv(M, 128);
    while ((nx * ny) & 7) ny++;
    dim3 g(nx, ny);
    k_mmw<<<g, 256, 0, stream>>>(A, Bh, Bl, K, bias, C, M, N, flags);
  };

  // 64x64-tile BK=32 gload_lds path (grid-starved / LDS-capped shapes)
  auto mms = [&](const bf16* A, const short* Bh, const short* Bl, int K,
                 const float* bias, bf16* C, int M, int N, int flags){
    int nx = N / 64;
    int ny = cdiv(M, 64);
    while ((nx * ny) & 7) ny++;
    dim3 g(nx, ny);
    k_mms<<<g, 256, 0, stream>>>(A, Bh, Bl, K, bias, C, M, N, flags);
  };

  hipMemsetAsync(diag, 0, (size_t)(4 + NN + 768) * 4, stream);

  // CSR build + norms
  k_ideg<<<cdiv(NE, 256), 256, 0, stream>>>(dst, ideg);
  k_scan1<<<NB, 256, 0, stream>>>(ideg, cursor, bsum);
  k_scan2<<<1, 128, 0, stream>>>(bsum, boff);
  k_scan3<<<NB, 256, 0, stream>>>(ideg, boff, rowptr, cursor, dg, dc, ic);
  k_fill<<<cdiv(NE, 256), 256, 0, stream>>>(src, dst, cursor, colsrc);

  // batched weight prep
  {
    WtPack p;
    const float* Ws[10] = {W1, W2, Wg1, Wg2, Wsl, Wsr, Wc0, Wc1, Wgat1, Wgat2};
    short* his[10] = {w1h, w2h, wg1h, wg2h, wslh, wsrh, wc0h, wc1h, wgat1h, wgat2h};
    short* los[10] = {w1l, w2l, wg1l, wg2l, wsll, wsrl, wc0l, wc1l, wgat1l, wgat2l};
    int Ks[10] = {128, 1024, 512, 256, 128, 128, 128, 128, 128, 128};
    int nss[10] = {10, 9, 8, 7, 7, 7, 7, 7, 8, 8};
    int off = 0;
    for (int i = 0; i < 10; i++){
      p.W[i] = Ws[i]; p.hi[i] = his[i]; p.lo[i] = los[i];
      p.K[i] = Ks[i]; p.nshift[i] = nss[i]; p.base[i] = off;
      off += Ks[i] << nss[i];
    }
    p.base[10] = off;
    k_wtall<<<cdiv(off, 256), 256, 0, stream>>>(p);
  }

  k_gather<<<cdiv(NN * 128, 256), 256, 0, stream>>>(uidx, iidx, ue, ie, x0b);

  // Phase A — MLP (MLP1 via k_mms: 5008 blocks, 8 blk/CU; MLP2 via k_mmw)
  if (h1rows == 20000){
    mms(x0b, w1h, w1l, 128, b1, h1b, 20000, 1024, GF_BIAS | GF_RELU);
    mmw(h1b, w2h, w2l, 1024, b2, h2b, 20000, 512, GF_BIAS | GF_RELU);
  } else {
    for (int ofs = 0; ofs < NN; ofs += 10000){
      mms(x0b + (size_t)ofs * 128, w1h, w1l, 128,
          b1, h1b, 10000, 1024, GF_BIAS | GF_RELU);
      mmw(h1b, w2h, w2l, 1024,
          b2, h2b + (size_t)ofs * 512, 10000, 512, GF_BIAS | GF_RELU);
    }
  }

  // Phase B — GCN1 (512->256) + BN + relu  (k_mms: 1252 blocks vs 628)
  mms(h2b, wg1h, wg1l, 512, nullptr, xw1b, NN, 256, 0);
  k_agg<<<cdiv(NN * 64, 256), 256, 0, stream>>>(rowptr, colsrc, xw1b, dg, nullptr, bg1, g1f, nullptr, 6, 0);
  k_bn_stats<<<cdiv(NN, 128), 256, 0, stream>>>(g1f, stats1, 256);
  k_bn_apply<<<cdiv(NN * 256, 256), 256, 0, stream>>>(g1f, stats1, gamma1, beta1, 8, NN * 256, g1b);

  // Phase C — GCN2 (256->128) + BN + relu  (k_mms: gload+swizzle)
  mms(g1b, wg2h, wg2l, 256, nullptr, xw2b, NN, 128, 0);
  k_agg<<<cdiv(NN * 32, 256), 256, 0, stream>>>(rowptr, colsrc, xw2b, dg, nullptr, bg2, x3f, nullptr, 5, 0);
  k_bn_stats<<<cdiv(NN, 128), 256, 0, stream>>>(x3f, stats2, 128);
  k_bn_apply<<<cdiv(NN * 128, 256), 256, 0, stream>>>(x3f, stats2, gamma2, beta2, 7, NN * 128, x3b);

  // Phase D — SAGE (npass=2 -> k_mm64)
  k_agg<<<cdiv(NN * 32, 256), 256, 0, stream>>>(rowptr, colsrc, x3b, nullptr, ic, nullptr, nullptr, aggb, 5, 1);
  mm(aggb, wslh, wsll, 128, x3b, wsrh, wsrl, 128, bsl, x4b, NN, 128, GF_BIAS | GF_RELU);

  // Phase E — Cheb (npass=2 -> k_mm64)
  k_agg<<<cdiv(NN * 32, 256), 256, 0, stream>>>(rowptr, colsrc, x4b, dc, nullptr, nullptr, nullptr, tx1b, 5, 2);
  mm(x4b, wc0h, wc0l, 128, tx1b, wc1h, wc1l, 128, bc, x5b, NN, 128, GF_BIAS | GF_RELU);

  // Phase F — GAT1 (projection via k_mms: 1252 blocks)
  mms(x5b, wgat1h, wgat1l, 128, nullptr, xpb, NN, 256, 0);
  k_gat_alar<<<cdiv(NN, 4), 256, 0, stream>>>(xpb, as1, ad1, al, ar);
  k_gat<<<cdiv(NN, 4), 256, 0, stream>>>(rowptr, colsrc, xpb, al, ar, bgat1, x6b,
                                         nullptr, nullptr, nullptr);
  k_chk_bf<<<256, 256, 0, stream>>>((const unsigned short*)x6b, NN * 128, 16, diag);

  // Phase G — GAT2 (final projection fused -> fp32 out)
  mms(x6b, wgat2h, wgat2l, 128, nullptr, xpb, NN, 256, 0);
  k_gat_alar<<<cdiv(NN, 4), 256, 0, stream>>>(xpb, as2, ad2, al, ar);
  k_gat<<<cdiv(NN, 4), 256, 0, stream>>>(rowptr, colsrc, xpb, al, ar, bgat2, nullptr,
                                         Wp, bp, (float*)d_out);
  k_diag_out<<<cdiv(NN, 256), 256, 0, stream>>>(diag, (float*)d_out);
}

// Round 11
// 570.204 us; speedup vs baseline: 1.0206x; 1.0206x over previous
//
#include <hip/hip_runtime.h>
#include <hip/hip_bf16.h>

typedef __hip_bfloat16 bf16;
typedef short s8v __attribute__((ext_vector_type(8)));
typedef float f4v __attribute__((ext_vector_type(4)));

#define NN 20000
#define NE 160000
#define BN_EPS 1e-5f
#define NB 79   // cdiv(NN,256)

#define GF_BIAS 1
#define GF_RELU 2

static __device__ __forceinline__ float b2f(const bf16 x){ return __bfloat162float(x); }
static __device__ __forceinline__ float bits2f(unsigned int u){ return __uint_as_float(u << 16); }
static __device__ __forceinline__ unsigned short f2bits(float f){
  bf16 h = __float2bfloat16(f);
  unsigned short u; __builtin_memcpy(&u, &h, 2); return u;
}
static __device__ __forceinline__ float lrelu(float v){ return (v > 0.f) ? v : 0.2f * v; }

static inline int cdiv(int a, int b){ return (a + b - 1) / b; }

// async global->LDS, 16B per lane (wave-uniform LDS base + lane*16; lanes of a
// wave pass contiguous lds ptrs so the linear layout matches).
static __device__ __forceinline__ void gload16(const short* g, short* l){
  __builtin_amdgcn_global_load_lds(
      (const __attribute__((address_space(1))) unsigned int*)g,
      (__attribute__((address_space(3))) unsigned int*)l, 16, 0, 0);
}

// ---------------- diagnostics ----------------

__global__ void k_chk_bf(const unsigned short* __restrict__ x, int n, int code,
                         int* __restrict__ diag){
  bool bad = false;
  for (int k = blockIdx.x * 256 + threadIdx.x; k < n; k += gridDim.x * 256)
    if ((x[k] & 0x7F80u) == 0x7F80u) bad = true;
  if (bad) atomicCAS(diag, 0, code);
}

__global__ void k_diag_out(const int* __restrict__ diag, float* __restrict__ out){
  int d = *diag;
  if (d == 0) return;
  int i = blockIdx.x * 256 + threadIdx.x;
  if (i < NN) out[i] = (float)(d * 100);
}

// ---------------- CSR build (hierarchical, coalesced) ----------------

__global__ void k_ideg(const int* __restrict__ dst, int* __restrict__ ideg){
  int e = blockIdx.x * 256 + threadIdx.x;
  if (e < NE) atomicAdd(&ideg[dst[e]], 1);
}

__global__ __launch_bounds__(256) void k_scan1(const int* __restrict__ ideg,
                                               int* __restrict__ tmp,
                                               int* __restrict__ bsum){
  __shared__ int lds[256];
  int tid = threadIdx.x;
  int i = blockIdx.x * 256 + tid;
  int v = (i < NN) ? ideg[i] : 0;
  lds[tid] = v;
  __syncthreads();
  for (int off = 1; off < 256; off <<= 1){
    int t = (tid >= off) ? lds[tid - off] : 0;
    __syncthreads();
    lds[tid] += t;
    __syncthreads();
  }
  if (i < NN) tmp[i] = lds[tid];
  if (tid == 255) bsum[blockIdx.x] = lds[255];
}

__global__ __launch_bounds__(128) void k_scan2(const int* __restrict__ bsum,
                                               int* __restrict__ boff){
  __shared__ int lds[128];
  int tid = threadIdx.x;
  int v = (tid < NB) ? bsum[tid] : 0;
  lds[tid] = v;
  __syncthreads();
  for (int off = 1; off < 128; off <<= 1){
    int t = (tid >= off) ? lds[tid - off] : 0;
    __syncthreads();
    lds[tid] += t;
    __syncthreads();
  }
  if (tid < NB) boff[tid] = lds[tid] - v;
}

__global__ __launch_bounds__(256) void k_scan3(const int* __restrict__ ideg,
                                               const int* __restrict__ boff,
                                               int* __restrict__ rowptr,
                                               int* __restrict__ cursor,
                                               float* __restrict__ dg,
                                               float* __restrict__ dc,
                                               float* __restrict__ ic){
  int i = blockIdx.x * 256 + threadIdx.x;
  if (i == 0) rowptr[NN] = NE;
  if (i >= NN) return;
  int v = ideg[i];
  int excl = cursor[i] - v + boff[blockIdx.x];
  rowptr[i] = excl;
  cursor[i] = excl;
  float d = (float)v;
  dg[i] = rsqrtf(d + 1.0f);
  dc[i] = (d > 0.f) ? rsqrtf(d) : 0.f;
  ic[i] = 1.0f / fmaxf(d, 1.0f);
}

__global__ void k_fill(const int* __restrict__ src, const int* __restrict__ dst,
                       int* __restrict__ cursor, int* __restrict__ colsrc){
  int e = blockIdx.x * 256 + threadIdx.x;
  if (e >= NE) return;
  int pos = atomicAdd(&cursor[dst[e]], 1);
  colsrc[pos] = src[e];
}

// ---- batched weight prep ----

struct WtPack {
  const float* W[10]; short* hi[10]; short* lo[10];
  int K[10]; int nshift[10]; int base[11];
};

__global__ __launch_bounds__(256) void k_wtall(WtPack p){
  int idx = blockIdx.x * 256 + threadIdx.x;
  if (idx >= p.base[10]) return;
  int seg = 0;
#pragma unroll
  for (int i = 1; i < 10; i++) seg += (idx >= p.base[i]) ? 1 : 0;
  int local = idx - p.base[seg];
  int K = p.K[seg], ns = p.nshift[seg];
  int n = local & ((1 << ns) - 1), k = local >> ns;
  float w = p.W[seg][local];
  unsigned short h = f2bits(w);
  unsigned short l = f2bits(w - bits2f(h));
  p.hi[seg][(size_t)n * K + k] = (short)h;
  p.lo[seg][(size_t)n * K + k] = (short)l;
}

// ---------------- gather ----------------

__global__ void k_gather(const int* __restrict__ uidx, const int* __restrict__ iidx,
                         const float* __restrict__ ue, const float* __restrict__ ie,
                         bf16* __restrict__ x0){
  int idx = blockIdx.x * 256 + threadIdx.x;
  if (idx >= NN * 128) return;
  int i = idx >> 7, c = idx & 127;
  float v = (c < 64) ? ue[(size_t)uidx[i] * 64 + c] : ie[(size_t)iidx[i] * 64 + (c - 64)];
  x0[idx] = __float2bfloat16(v);
}

// ------- MFMA GEMM, 64x64 tile, hi/lo fused, reg-staging (GCN2/SAGE/Cheb) -------

__global__ __launch_bounds__(256) void k_mm64(
    const bf16* A0, const short* B0h, const short* B0l, int K0,
    const bf16* A1, const short* B1h, const short* B1l, int K1,
    const float* __restrict__ bias, bf16* __restrict__ C,
    int M, int Ncol, int flags, int npass){
  __shared__ short As[64][72];    // 64 K-shorts + 8 pad (16B-aligned rows)
  __shared__ short Bhs[64][72];
  __shared__ short Bls[64][72];
  const int tid = threadIdx.x;
  const int bid = blockIdx.y * gridDim.x + blockIdx.x;
  const int total = gridDim.x * gridDim.y;
  const int L = (bid & 7) * (total >> 3) + (bid >> 3);
  const int row0 = (L / gridDim.x) * 64, col0 = (L % gridDim.x) * 64;
  if (row0 >= M) return;
  const int wid = tid >> 6, lane = tid & 63;
  const int wr = (wid >> 1) * 32, wc = (wid & 1) * 32;
  const int lr = lane & 15, lq = lane >> 4;
  const int sr = tid >> 2, sq = (tid & 3) * 16;  // staging: row sr, 16 shorts from sq

  f4v acc[2][2];
#pragma unroll
  for (int i = 0; i < 2; i++)
#pragma unroll
    for (int j = 0; j < 2; j++)
      acc[i][j] = f4v{0.f, 0.f, 0.f, 0.f};

  const bf16* Aarr[2] = {A0, A1};
  const short* Bharr[2] = {B0h, B1h};
  const short* Blarr[2] = {B0l, B1l};
  const int Karr[2] = {K0, K1};

  const bool arow_ok = (row0 + sr) < M;

  for (int p = 0; p < npass; p++){
    const short* A = (const short*)Aarr[p];
    const short* Bh = Bharr[p];
    const short* Bl = Blarr[p];
    const int K = Karr[p];
    const short* arow = A + (size_t)(row0 + sr) * K + sq;
    const short* bhrow = Bh + (size_t)(col0 + sr) * K + sq;
    const short* blrow = Bl + (size_t)(col0 + sr) * K + sq;

    // prologue: load tile k0=0 into registers
    uint4 ra0 = make_uint4(0,0,0,0), ra1 = make_uint4(0,0,0,0);
    if (arow_ok){ ra0 = *(const uint4*)(arow); ra1 = *(const uint4*)(arow + 8); }
    uint4 rb0 = *(const uint4*)(bhrow), rb1 = *(const uint4*)(bhrow + 8);
    uint4 rc0 = *(const uint4*)(blrow), rc1 = *(const uint4*)(blrow + 8);

    for (int k0 = 0; k0 < K; k0 += 64){
      // commit staged registers to LDS
      *(uint4*)&As[sr][sq] = ra0;  *(uint4*)&As[sr][sq + 8] = ra1;
      *(uint4*)&Bhs[sr][sq] = rb0; *(uint4*)&Bhs[sr][sq + 8] = rb1;
      *(uint4*)&Bls[sr][sq] = rc0; *(uint4*)&Bls[sr][sq + 8] = rc1;
      __syncthreads();
      // prefetch next tile while this one computes (overlaps global latency)
      if (k0 + 64 < K){
        int off = k0 + 64;
        if (arow_ok){ ra0 = *(const uint4*)(arow + off); ra1 = *(const uint4*)(arow + off + 8); }
        rb0 = *(const uint4*)(bhrow + off); rb1 = *(const uint4*)(bhrow + off + 8);
        rc0 = *(const uint4*)(blrow + off); rc1 = *(const uint4*)(blrow + off + 8);
      }
#pragma unroll
      for (int t = 0; t < 2; t++){
        s8v a[2], bh2[2], bl2[2];
#pragma unroll
        for (int i = 0; i < 2; i++) a[i] = *(const s8v*)&As[wr + i * 16 + lr][t * 32 + lq * 8];
#pragma unroll
        for (int j = 0; j < 2; j++){
          bh2[j] = *(const s8v*)&Bhs[wc + j * 16 + lr][t * 32 + lq * 8];
          bl2[j] = *(const s8v*)&Bls[wc + j * 16 + lr][t * 32 + lq * 8];
        }
#pragma unroll
        for (int i = 0; i < 2; i++)
#pragma unroll
          for (int j = 0; j < 2; j++){
            acc[i][j] = __builtin_amdgcn_mfma_f32_16x16x32_bf16(a[i], bh2[j], acc[i][j], 0, 0, 0);
            acc[i][j] = __builtin_amdgcn_mfma_f32_16x16x32_bf16(a[i], bl2[j], acc[i][j], 0, 0, 0);
          }
      }
      __syncthreads();
    }
  }

#pragma unroll
  for (int i = 0; i < 2; i++){
#pragma unroll
    for (int rg = 0; rg < 4; rg++){
      int row = row0 + wr + i * 16 + lq * 4 + rg;
      if (row >= M) continue;
#pragma unroll
      for (int j = 0; j < 2; j++){
        int col = col0 + wc + j * 16 + lr;
        float v = acc[i][j][rg];
        if (flags & GF_BIAS) v += bias[col];
        if (flags & GF_RELU) v = fmaxf(v, 0.f);
        C[(size_t)row * Ncol + col] = __float2bfloat16(v);
      }
    }
  }
}

// ------- MFMA GEMM, 128x64 tile, gload_lds staging + involution swizzle -------
// Best-measured config (R7/R9): 32KB LDS, 5 blk/CU, 2 barriers/K-step,
// conflicts 0 (PMC-verified), ~594 TF on merged MLP2. The R10 BM=64/BK=32
// variant regressed (+10.5 us): smaller tiles lose B-panel amortization and
// double barrier count -- tile space is now fully mapped, this is the optimum
// for the 2-barrier structure.

__global__ __launch_bounds__(256) void k_mmw(
    const bf16* A0, const short* B0h, const short* B0l, int K,
    const float* __restrict__ bias, bf16* __restrict__ C,
    int M, int Ncol, int flags){
  __shared__ short As[128 * 64];
  __shared__ short Bhs[64 * 64];
  __shared__ short Bls[64 * 64];
  const int tid = threadIdx.x;
  const int bid = blockIdx.y * gridDim.x + blockIdx.x;
  const int total = gridDim.x * gridDim.y;
  const int L = (bid & 7) * (total >> 3) + (bid >> 3);
  const int row0 = (L / gridDim.x) * 128, col0 = (L % gridDim.x) * 64;
  if (row0 >= M) return;
  const int wid = tid >> 6, lane = tid & 63;
  const int wr2 = (wid >> 1) * 64, wc2 = (wid & 1) * 32;
  const int lr = lane & 15, lq = lane >> 4;
  const int rx = lr & 7;    // read-side XOR key (row & 7 == lr & 7 here)

  f4v acc[4][2];
#pragma unroll
  for (int i = 0; i < 4; i++)
#pragma unroll
    for (int j = 0; j < 2; j++)
      acc[i][j] = f4v{0.f, 0.f, 0.f, 0.f};

  // staging: A = 1024 chunks (128 rows x 8), B = 512 chunks each.
  // LDS chunk (r,c) holds GLOBAL chunk c ^ (r&7) of row r (involution).
  const short* A = (const short*)A0;
  const short* asrc[4]; int adst[4];
#pragma unroll
  for (int i = 0; i < 4; i++){
    int ci = i * 256 + tid;
    int r = ci >> 3, sg = ci & 7;
    int ar = row0 + r; if (ar > M - 1) ar = M - 1;   // clamp ragged M
    asrc[i] = A + (size_t)ar * K + ((sg ^ (r & 7)) * 8);
    adst[i] = ci * 8;
  }
  const short* bhsrc[2]; const short* blsrc[2]; int bdst[2];
#pragma unroll
  for (int i = 0; i < 2; i++){
    int ci = i * 256 + tid;
    int r = ci >> 3, sg = ci & 7;
    int sc = (sg ^ (r & 7)) * 8;
    bhsrc[i] = B0h + (size_t)(col0 + r) * K + sc;
    blsrc[i] = B0l + (size_t)(col0 + r) * K + sc;
    bdst[i] = ci * 8;
  }

  for (int k0 = 0; k0 < K; k0 += 64){
    __syncthreads();      // all waves done reading LDS before overwrite
#pragma unroll
    for (int i = 0; i < 4; i++) gload16(asrc[i] + k0, As + adst[i]);
#pragma unroll
    for (int i = 0; i < 2; i++){
      gload16(bhsrc[i] + k0, Bhs + bdst[i]);
      gload16(blsrc[i] + k0, Bls + bdst[i]);
    }
    __syncthreads();      // compiler drains vmcnt(0) before s_barrier
#pragma unroll
    for (int t = 0; t < 2; t++){
      s8v a[4], bh2[2], bl2[2];
      const int ch0 = (((t << 2) | lq) ^ rx) * 8;   // swizzled chunk offset
#pragma unroll
      for (int i = 0; i < 4; i++)
        a[i] = *(const s8v*)&As[(wr2 + i * 16 + lr) * 64 + ch0];
#pragma unroll
      for (int j = 0; j < 2; j++){
        bh2[j] = *(const s8v*)&Bhs[(wc2 + j * 16 + lr) * 64 + ch0];
        bl2[j] = *(const s8v*)&Bls[(wc2 + j * 16 + lr) * 64 + ch0];
      }
#pragma unroll
      for (int i = 0; i < 4; i++)
#pragma unroll
        for (int j = 0; j < 2; j++){
          acc[i][j] = __builtin_amdgcn_mfma_f32_16x16x32_bf16(a[i], bh2[j], acc[i][j], 0, 0, 0);
          acc[i][j] = __builtin_amdgcn_mfma_f32_16x16x32_bf16(a[i], bl2[j], acc[i][j], 0, 0, 0);
        }
    }
  }

#pragma unroll
  for (int i = 0; i < 4; i++){
#pragma unroll
    for (int rg = 0; rg < 4; rg++){
      int row = row0 + wr2 + i * 16 + lq * 4 + rg;
      if (row >= M) continue;
#pragma unroll
      for (int j = 0; j < 2; j++){
        int col = col0 + wc2 + j * 16 + lr;
        float v = acc[i][j][rg];
        if (flags & GF_BIAS) v += bias[col];
        if (flags & GF_RELU) v = fmaxf(v, 0.f);
        C[(size_t)row * Ncol + col] = __float2bfloat16(v);
      }
    }
  }
}

// ------- CSR aggregation: 4 cols/thread, 4-edge batched -------

__global__ __launch_bounds__(256) void k_agg(
    const int* __restrict__ rowptr, const int* __restrict__ colsrc,
    const bf16* __restrict__ x, const float* __restrict__ wn,
    const float* __restrict__ icv, const float* __restrict__ bias,
    float* __restrict__ outf, bf16* __restrict__ outb,
    int qshift, int mode){
  int idx = blockIdx.x * 256 + threadIdx.x;
  int total = NN << qshift;
  if (idx >= total) return;
  int d = idx >> qshift, q = idx & ((1 << qshift) - 1);
  int F = 4 << qshift;
  int c = q * 4;
  int r0 = rowptr[d], r1 = rowptr[d + 1];
  float s0 = 0.f, s1 = 0.f, s2 = 0.f, s3 = 0.f;
  const short* xs = (const short*)x;
  for (int r = r0; r < r1; r += 4){
    int n = r1 - r;
    int i0 = colsrc[r];
    int i1 = (n > 1) ? colsrc[r + 1] : 0;
    int i2 = (n > 2) ? colsrc[r + 2] : 0;
    int i3 = (n > 3) ? colsrc[r + 3] : 0;
    float w0 = (mode == 1) ? 1.f : wn[i0];
    float w1 = (n > 1) ? ((mode == 1) ? 1.f : wn[i1]) : 0.f;
    float w2 = (n > 2) ? ((mode == 1) ? 1.f : wn[i2]) : 0.f;
    float w3 = (n > 3) ? ((mode == 1) ? 1.f : wn[i3]) : 0.f;
    uint2 v0 = *(const uint2*)(xs + (size_t)i0 * F + c);
    uint2 v1 = *(const uint2*)(xs + (size_t)i1 * F + c);
    uint2 v2 = *(const uint2*)(xs + (size_t)i2 * F + c);
    uint2 v3 = *(const uint2*)(xs + (size_t)i3 * F + c);
    s0 += w0 * bits2f(v0.x & 0xffffu) + w1 * bits2f(v1.x & 0xffffu)
        + w2 * bits2f(v2.x & 0xffffu) + w3 * bits2f(v3.x & 0xffffu);
    s1 += w0 * bits2f(v0.x >> 16) + w1 * bits2f(v1.x >> 16)
        + w2 * bits2f(v2.x >> 16) + w3 * bits2f(v3.x >> 16);
    s2 += w0 * bits2f(v0.y & 0xffffu) + w1 * bits2f(v1.y & 0xffffu)
        + w2 * bits2f(v2.y & 0xffffu) + w3 * bits2f(v3.y & 0xffffu);
    s3 += w0 * bits2f(v0.y >> 16) + w1 * bits2f(v1.y >> 16)
        + w2 * bits2f(v2.y >> 16) + w3 * bits2f(v3.y >> 16);
  }
  if (mode == 0){
    float w = wn[d], w2 = w * w;
    uint2 vd = *(const uint2*)(xs + (size_t)d * F + c);
    float4 o;
    o.x = w * s0 + w2 * bits2f(vd.x & 0xffffu) + bias[c + 0];
    o.y = w * s1 + w2 * bits2f(vd.x >> 16)     + bias[c + 1];
    o.z = w * s2 + w2 * bits2f(vd.y & 0xffffu) + bias[c + 2];
    o.w = w * s3 + w2 * bits2f(vd.y >> 16)     + bias[c + 3];
    *(float4*)(outf + (size_t)d * F + c) = o;
  } else {
    float m = (mode == 1) ? icv[d] : -wn[d];
    unsigned int lo = (unsigned int)f2bits(s0 * m) | ((unsigned int)f2bits(s1 * m) << 16);
    unsigned int hi = (unsigned int)f2bits(s2 * m) | ((unsigned int)f2bits(s3 * m) << 16);
    *(uint2*)((short*)outb + (size_t)d * F + c) = make_uint2(lo, hi);
  }
}

// ---------------- batchnorm ----------------

__global__ void k_bn_stats(const float* __restrict__ x, float* __restrict__ stats, int F){
  int c = threadIdx.x & (F - 1);
  int rsub = threadIdx.x / F;
  int rpi = 256 / F;
  int r0 = blockIdx.x * 128;
  int rend = min(NN, r0 + 128);
  float s1 = 0.f, s2 = 0.f;
  for (int r = r0 + rsub; r < rend; r += rpi){
    float v = x[(size_t)r * F + c];
    s1 += v; s2 += v * v;
  }
  atomicAdd(&stats[c], s1);
  atomicAdd(&stats[F + c], s2);
}

__global__ void k_bn_apply(const float* __restrict__ x, const float* __restrict__ stats,
                           const float* __restrict__ g, const float* __restrict__ b,
                           int fshift, int total, bf16* __restrict__ out){
  int idx = blockIdx.x * 256 + threadIdx.x;
  if (idx >= total) return;
  int F = 1 << fshift;
  int c = idx & (F - 1);
  float mu = stats[c] * (1.0f / NN);
  float var = fmaxf(stats[F + c] * (1.0f / NN) - mu * mu, 0.f);
  float v = (x[idx] - mu) * rsqrtf(var + BN_EPS) * g[c] + b[c];
  out[idx] = __float2bfloat16(fmaxf(v, 0.f));
}

// ---------------- GAT ----------------

__global__ __launch_bounds__(256) void k_gat_alar(const bf16* __restrict__ xp,
                                                  const float* __restrict__ as_,
                                                  const float* __restrict__ ad_,
                                                  float* __restrict__ al,
                                                  float* __restrict__ ar){
  int d = blockIdx.x * 4 + (threadIdx.x >> 6);
  int lane = threadIdx.x & 63;
  if (d >= NN) return;
  int c0 = lane * 2;
  unsigned int p0 = *(const unsigned int*)((const short*)xp + (size_t)d * 256 + c0);
  unsigned int p1 = *(const unsigned int*)((const short*)xp + (size_t)d * 256 + 128 + c0);
  float x00 = bits2f(p0 & 0xffffu), x01 = bits2f(p0 >> 16);
  float x10 = bits2f(p1 & 0xffffu), x11 = bits2f(p1 >> 16);
  float sa0 = x00 * as_[c0] + x01 * as_[c0 + 1];
  float sd0 = x00 * ad_[c0] + x01 * ad_[c0 + 1];
  float sa1 = x10 * as_[128 + c0] + x11 * as_[128 + c0 + 1];
  float sd1 = x10 * ad_[128 + c0] + x11 * ad_[128 + c0 + 1];
#pragma unroll
  for (int off = 32; off > 0; off >>= 1){
    sa0 += __shfl_xor(sa0, off); sd0 += __shfl_xor(sd0, off);
    sa1 += __shfl_xor(sa1, off); sd1 += __shfl_xor(sd1, off);
  }
  if (lane == 0){
    al[d * 2] = sa0;     ar[d * 2] = sd0;
    al[d * 2 + 1] = sa1; ar[d * 2 + 1] = sd1;
  }
}

// Online-softmax single-pass GAT, 4 nodes/block (1 wave each), ZERO LDS.
// Broadcasts via __shfl; lanes >= nt carry w=0 so their edges contribute 0.

__global__ __launch_bounds__(256) void k_gat(const int* __restrict__ rowptr,
                                             const int* __restrict__ colsrc,
                                             const bf16* __restrict__ xp,
                                             const float* __restrict__ al,
                                             const float* __restrict__ ar,
                                             const float* __restrict__ bias,
                                             bf16* __restrict__ outb,
                                             const float* __restrict__ wp,
                                             const float* __restrict__ bp,
                                             float* __restrict__ outf){
  int lane = threadIdx.x & 63;
  int d = blockIdx.x * 4 + (threadIdx.x >> 6);
  if (d >= NN) return;
  int r0 = rowptr[d], r1 = rowptr[d + 1];
  float ard0 = ar[d * 2], ard1 = ar[d * 2 + 1];
  float e0 = lrelu(al[d * 2] + ard0);
  float e1 = lrelu(al[d * 2 + 1] + ard1);
  float m0 = e0, m1 = e1;                 // running max (uniform across lanes)
  float ps0 = (lane == 0) ? 1.f : 0.f;    // self term: exp(e0 - m0) = 1
  float ps1 = ps0;
  int c0 = lane * 2;
  float a00, a01, a10, a11;               // PV accum at weight exp(e_self-m)=1
  {
    unsigned int p0 = *(const unsigned int*)((const short*)xp + (size_t)d * 256 + c0);
    unsigned int p1 = *(const unsigned int*)((const short*)xp + (size_t)d * 256 + 128 + c0);
    a00 = bits2f(p0 & 0xffffu); a01 = bits2f(p0 >> 16);
    a10 = bits2f(p1 & 0xffffu); a11 = bits2f(p1 >> 16);
  }
  for (int t0 = r0; t0 < r1; t0 += 64){
    int nt = min(64, r1 - t0);
    float el0 = -3.4e38f, el1 = -3.4e38f;
    int s = 0;
    if (lane < nt){
      s = colsrc[t0 + lane];
      el0 = lrelu(al[s * 2] + ard0);
      el1 = lrelu(al[s * 2 + 1] + ard1);
    }
    // chunk max via shfl (in-register)
    float cm0 = el0, cm1 = el1;
#pragma unroll
    for (int off = 32; off > 0; off >>= 1){
      cm0 = fmaxf(cm0, __shfl_xor(cm0, off));
      cm1 = fmaxf(cm1, __shfl_xor(cm1, off));
    }
    float n0 = fmaxf(m0, cm0), n1 = fmaxf(m1, cm1);
    float sc0 = expf(m0 - n0), sc1 = expf(m1 - n1);
    ps0 *= sc0; ps1 *= sc1;
    a00 *= sc0; a01 *= sc0; a10 *= sc1; a11 *= sc1;
    m0 = n0; m1 = n1;
    // each lane computes ITS edge's weight once; denominator contribution
    float w0 = 0.f, w1 = 0.f;
    if (lane < nt){
      w0 = expf(el0 - m0);
      w1 = expf(el1 - m1);
      ps0 += w0; ps1 += w1;
    }
    // PV: 4-edge batched, broadcast via shfl (no LDS, no barriers)
    for (int r = 0; r < nt; r += 4){
      int sA = __shfl(s, r);     float wA0 = __shfl(w0, r),     wA1 = __shfl(w1, r);
      int sB = __shfl(s, r + 1); float wB0 = __shfl(w0, r + 1), wB1 = __shfl(w1, r + 1);
      int sC = __shfl(s, r + 2); float wC0 = __shfl(w0, r + 2), wC1 = __shfl(w1, r + 2);
      int sD = __shfl(s, r + 3); float wD0 = __shfl(w0, r + 3), wD1 = __shfl(w1, r + 3);
      unsigned int pA0 = *(const unsigned int*)((const short*)xp + (size_t)sA * 256 + c0);
      unsigned int pA1 = *(const unsigned int*)((const short*)xp + (size_t)sA * 256 + 128 + c0);
      unsigned int pB0 = *(const unsigned int*)((const short*)xp + (size_t)sB * 256 + c0);
      unsigned int pB1 = *(const unsigned int*)((const short*)xp + (size_t)sB * 256 + 128 + c0);
      unsigned int pC0 = *(const unsigned int*)((const short*)xp + (size_t)sC * 256 + c0);
      unsigned int pC1 = *(const unsigned int*)((const short*)xp + (size_t)sC * 256 + 128 + c0);
      unsigned int pD0 = *(const unsigned int*)((const short*)xp + (size_t)sD * 256 + c0);
      unsigned int pD1 = *(const unsigned int*)((const short*)xp + (size_t)sD * 256 + 128 + c0);
      a00 += wA0 * bits2f(pA0 & 0xffffu) + wB0 * bits2f(pB0 & 0xffffu)
           + wC0 * bits2f(pC0 & 0xffffu) + wD0 * bits2f(pD0 & 0xffffu);
      a01 += wA0 * bits2f(pA0 >> 16) + wB0 * bits2f(pB0 >> 16)
           + wC0 * bits2f(pC0 >> 16) + wD0 * bits2f(pD0 >> 16);
      a10 += wA1 * bits2f(pA1 & 0xffffu) + wB1 * bits2f(pB1 & 0xffffu)
           + wC1 * bits2f(pC1 & 0xffffu) + wD1 * bits2f(pD1 & 0xffffu);
      a11 += wA1 * bits2f(pA1 >> 16) + wB1 * bits2f(pB1 >> 16)
           + wC1 * bits2f(pC1 >> 16) + wD1 * bits2f(pD1 >> 16);
    }
  }
#pragma unroll
  for (int off = 32; off > 0; off >>= 1){
    ps0 += __shfl_xor(ps0, off);
    ps1 += __shfl_xor(ps1, off);
  }
  float v0 = 0.5f * (a00 / ps0 + a10 / ps1) + bias[c0];
  float v1 = 0.5f * (a01 / ps0 + a11 / ps1) + bias[c0 + 1];
  v0 = (v0 > 0.f) ? v0 : expm1f(v0);
  v1 = (v1 > 0.f) ? v1 : expm1f(v1);
  if (wp == nullptr){
    unsigned int packed = (unsigned int)f2bits(v0) | ((unsigned int)f2bits(v1) << 16);
    *(unsigned int*)((short*)outb + (size_t)d * 128 + c0) = packed;
  } else {
    float pv = v0 * wp[c0] + v1 * wp[c0 + 1];
#pragma unroll
    for (int off = 32; off > 0; off >>= 1) pv += __shfl_down(pv, off);
    if (lane == 0) outf[d] = pv + bp[0];
  }
}

// ---------------- host ----------------

extern "C" void kernel_launch(void* const* d_in, const int* in_sizes, int n_in,
                              void* d_out, int out_size, void* d_ws, size_t ws_size,
                              hipStream_t stream){
  const int* uidx = (const int*)d_in[0];
  const int* iidx = (const int*)d_in[1];
  const int* eidx = (const int*)d_in[2];
  const int* src = eidx;
  const int* dst = eidx + NE;
  const float* ue  = (const float*)d_in[3];
  const float* ie  = (const float*)d_in[4];
  const float* W1  = (const float*)d_in[5];  const float* b1  = (const float*)d_in[6];
  const float* W2  = (const float*)d_in[7];  const float* b2  = (const float*)d_in[8];
  const float* Wg1 = (const float*)d_in[9];  const float* bg1 = (const float*)d_in[10];
  const float* gamma1 = (const float*)d_in[11]; const float* beta1 = (const float*)d_in[12];
  const float* Wg2 = (const float*)d_in[13]; const float* bg2 = (const float*)d_in[14];
  const float* gamma2 = (const float*)d_in[15]; const float* beta2 = (const float*)d_in[16];
  const float* Wsl = (const float*)d_in[17]; const float* bsl = (const float*)d_in[18];
  const float* Wsr = (const float*)d_in[19];
  const float* Wc0 = (const float*)d_in[20]; const float* Wc1 = (const float*)d_in[21];
  const float* bc  = (const float*)d_in[22];
  const float* Wgat1 = (const float*)d_in[23]; const float* as1 = (const float*)d_in[24];
  const float* ad1 = (const float*)d_in[25];   const float* bgat1 = (const float*)d_in[26];
  const float* Wgat2 = (const float*)d_in[27]; const float* as2 = (const float*)d_in[28];
  const float* ad2 = (const float*)d_in[29];   const float* bgat2 = (const float*)d_in[30];
  const float* Wp  = (const float*)d_in[31];   const float* bp  = (const float*)d_in[32];

  // ---- workspace ----
  int* diag   = (int*)d_ws;
  int* ideg   = diag + 4;
  float* stats1 = (float*)(ideg + NN);
  float* stats2 = stats1 + 512;
  int* bsum   = (int*)(stats2 + 256);
  int* boff   = bsum + 128;
  int* rowptr = boff + 128;
  int* cursor = rowptr + NN + 4;
  int* colsrc = cursor + NN;
  float* dg = (float*)(colsrc + NE);
  float* dc = dg + NN;
  float* ic = dc + NN;
  float* al = ic + NN;
  float* ar = al + 2 * NN;
  short* w1h = (short*)(ar + 2 * NN);
  short* w1l = w1h + 131072;
  short* w2h = w1l + 131072;
  short* w2l = w2h + 524288;
  short* wg1h = w2l + 524288;
  short* wg1l = wg1h + 131072;
  short* wg2h = wg1l + 131072;
  short* wg2l = wg2h + 32768;
  short* wslh = wg2l + 32768;
  short* wsll = wslh + 16384;
  short* wsrh = wsll + 16384;
  short* wsrl = wsrh + 16384;
  short* wc0h = wsrl + 16384;
  short* wc0l = wc0h + 16384;
  short* wc1h = wc0l + 16384;
  short* wc1l = wc1h + 16384;
  short* wgat1h = wc1l + 16384;
  short* wgat1l = wgat1h + 32768;
  short* wgat2h = wgat1l + 32768;
  short* wgat2l = wgat2h + 32768;
  short* X0 = wgat2l + 32768;
  short* H1 = X0 + (size_t)NN * 128;

  // MLP intermediate H1: prefer single-shot M=20000 (occupancy lever).
  size_t h1rows = 20000;
  short* H2 = H1 + h1rows * 1024;
  {
    size_t need = (size_t)((char*)(H2 + (size_t)NN * 512) - (char*)d_ws);
    if (need > ws_size){
      h1rows = 10000;
      H2 = H1 + h1rows * 1024;
    }
  }

  bf16* x0b  = (bf16*)X0;
  bf16* h1b  = (bf16*)H1;
  bf16* h2b  = (bf16*)H2;
  bf16* xw1b = (bf16*)H1;
  float* g1f = (float*)H2;
  bf16* g1b  = (bf16*)(H1 + (size_t)NN * 256);
  bf16* xw2b = (bf16*)X0;
  float* x3f = (float*)H1;
  bf16* x3b  = (bf16*)H2;
  bf16* aggb = (bf16*)X0;
  bf16* x4b  = (bf16*)(H2 + (size_t)NN * 128);
  bf16* tx1b = (bf16*)X0;
  bf16* x5b  = (bf16*)(H2 + (size_t)NN * 256);
  bf16* xpb  = (bf16*)H1;
  bf16* x6b  = (bf16*)X0;

  auto mm = [&](const bf16* A1, const short* B1h, const short* B1l, int K1,
                const bf16* A2, const short* B2h, const short* B2l, int K2,
                const float* bias, bf16* C, int M, int N, int flags){
    int nx = N / 64;
    int ny = cdiv(M, 64);
    while ((nx * ny) & 7) ny++;
    dim3 g(nx, ny);
    int np = A2 ? 2 : 1;
    k_mm64<<<g, 256, 0, stream>>>(A1, B1h, B1l, K1, A2, B2h, B2l, K2,
                                  bias, C, M, N, flags, np);
  };

  // 128x64-tile gload_lds path for N % 64 == 0, N >= 256
  auto mmw = [&](const bf16* A, const short* Bh, const short* Bl, int K,
                 const float* bias, bf16* C, int M, int N, int flags){
    int nx = N / 64;
    int ny = cdiv(M, 128);
    while ((nx * ny) & 7) ny++;
    dim3 g(nx, ny);
    k_mmw<<<g, 256, 0, stream>>>(A, Bh, Bl, K, bias, C, M, N, flags);
  };

  hipMemsetAsync(diag, 0, (size_t)(4 + NN + 768) * 4, stream);

  // CSR build + norms
  k_ideg<<<cdiv(NE, 256), 256, 0, stream>>>(dst, ideg);
  k_scan1<<<NB, 256, 0, stream>>>(ideg, cursor, bsum);
  k_scan2<<<1, 128, 0, stream>>>(bsum, boff);
  k_scan3<<<NB, 256, 0, stream>>>(ideg, boff, rowptr, cursor, dg, dc, ic);
  k_fill<<<cdiv(NE, 256), 256, 0, stream>>>(src, dst, cursor, colsrc);

  // batched weight prep
  {
    WtPack p;
    const float* Ws[10] = {W1, W2, Wg1, Wg2, Wsl, Wsr, Wc0, Wc1, Wgat1, Wgat2};
    short* his[10] = {w1h, w2h, wg1h, wg2h, wslh, wsrh, wc0h, wc1h, wgat1h, wgat2h};
    short* los[10] = {w1l, w2l, wg1l, wg2l, wsll, wsrl, wc0l, wc1l, wgat1l, wgat2l};
    int Ks[10] = {128, 1024, 512, 256, 128, 128, 128, 128, 128, 128};
    int nss[10] = {10, 9, 8, 7, 7, 7, 7, 7, 8, 8};
    int off = 0;
    for (int i = 0; i < 10; i++){
      p.W[i] = Ws[i]; p.hi[i] = his[i]; p.lo[i] = los[i];
      p.K[i] = Ks[i]; p.nshift[i] = nss[i]; p.base[i] = off;
      off += Ks[i] << nss[i];
    }
    p.base[10] = off;
    k_wtall<<<cdiv(off, 256), 256, 0, stream>>>(p);
  }

  k_gather<<<cdiv(NN * 128, 256), 256, 0, stream>>>(uidx, iidx, ue, ie, x0b);

  // Phase A — MLP
  if (h1rows == 20000){
    mmw(x0b, w1h, w1l, 128, b1, h1b, 20000, 1024, GF_BIAS | GF_RELU);
    mmw(h1b, w2h, w2l, 1024, b2, h2b, 20000, 512, GF_BIAS | GF_RELU);
  } else {
    for (int ofs = 0; ofs < NN; ofs += 10000){
      mmw(x0b + (size_t)ofs * 128, w1h, w1l, 128,
          b1, h1b, 10000, 1024, GF_BIAS | GF_RELU);
      mmw(h1b, w2h, w2l, 1024,
          b2, h2b + (size_t)ofs * 512, 10000, 512, GF_BIAS | GF_RELU);
    }
  }

  // Phase B — GCN1 (512->256) + BN + relu
  mmw(h2b, wg1h, wg1l, 512, nullptr, xw1b, NN, 256, 0);
  k_agg<<<cdiv(NN * 64, 256), 256, 0, stream>>>(rowptr, colsrc, xw1b, dg, nullptr, bg1, g1f, nullptr, 6, 0);
  k_bn_stats<<<cdiv(NN, 128), 256, 0, stream>>>(g1f, stats1, 256);
  k_bn_apply<<<cdiv(NN * 256, 256), 256, 0, stream>>>(g1f, stats1, gamma1, beta1, 8, NN * 256, g1b);

  // Phase C — GCN2 (256->128) + BN + relu  (N=128 -> 64-tile kernel)
  mm(g1b, wg2h, wg2l, 256, nullptr, nullptr, nullptr, 0, nullptr, xw2b, NN, 128, 0);
  k_agg<<<cdiv(NN * 32, 256), 256, 0, stream>>>(rowptr, colsrc, xw2b, dg, nullptr, bg2, x3f, nullptr, 5, 0);
  k_bn_stats<<<cdiv(NN, 128), 256, 0, stream>>>(x3f, stats2, 128);
  k_bn_apply<<<cdiv(NN * 128, 256), 256, 0, stream>>>(x3f, stats2, gamma2, beta2, 7, NN * 128, x3b);

  // Phase D — SAGE (npass=2, N=128 -> 64-tile kernel)
  k_agg<<<cdiv(NN * 32, 256), 256, 0, stream>>>(rowptr, colsrc, x3b, nullptr, ic, nullptr, nullptr, aggb, 5, 1);
  mm(aggb, wslh, wsll, 128, x3b, wsrh, wsrl, 128, bsl, x4b, NN, 128, GF_BIAS | GF_RELU);

  // Phase E — Cheb (npass=2, N=128 -> 64-tile kernel)
  k_agg<<<cdiv(NN * 32, 256), 256, 0, stream>>>(rowptr, colsrc, x4b, dc, nullptr, nullptr, nullptr, tx1b, 5, 2);
  mm(x4b, wc0h, wc0l, 128, tx1b, wc1h, wc1l, 128, bc, x5b, NN, 128, GF_BIAS | GF_RELU);

  // Phase F — GAT1
  mmw(x5b, wgat1h, wgat1l, 128, nullptr, xpb, NN, 256, 0);
  k_gat_alar<<<cdiv(NN, 4), 256, 0, stream>>>(xpb, as1, ad1, al, ar);
  k_gat<<<cdiv(NN, 4), 256, 0, stream>>>(rowptr, colsrc, xpb, al, ar, bgat1, x6b,
                                         nullptr, nullptr, nullptr);
  k_chk_bf<<<256, 256, 0, stream>>>((const unsigned short*)x6b, NN * 128, 16, diag);

  // Phase G — GAT2 (final projection fused -> fp32 out)
  mmw(x6b, wgat2h, wgat2l, 128, nullptr, xpb, NN, 256, 0);
  k_gat_alar<<<cdiv(NN, 4), 256, 0, stream>>>(xpb, as2, ad2, al, ar);
  k_gat<<<cdiv(NN, 4), 256, 0, stream>>>(rowptr, colsrc, xpb, al, ar, bgat2, nullptr,
                                         Wp, bp, (float*)d_out);
  k_diag_out<<<cdiv(NN, 256), 256, 0, stream>>>(diag, (float*)d_out);
}